// Round 1
// baseline (229.819 us; speedup 1.0000x reference)
//
#include <hip/hip_runtime.h>
#include <math.h>

// Problem constants (reference: S=256, B=2, HID=512, NH=8, HD=64, C=1)
constexpr int S_   = 256;
constexpr int B_   = 2;
constexpr int HID_ = 512;
constexpr int NH_  = 8;
constexpr int HD_  = 64;
constexpr int RPB_ = 8;   // rows per block in qkv kernel (W-traffic amortization)

__device__ __forceinline__ float artanh_c(float x) {
    // reference _artanh: clip to [-1+1e-7, 1-1e-7], then artanh
    x = fminf(fmaxf(x, -0.9999999f), 0.9999999f);
    return 0.5f * __logf((1.f + x) / (1.f - x));
}

__device__ __forceinline__ float block_sum_256(float v, float* red) {
    const int t = threadIdx.x;
    __syncthreads();              // protect previous use of red
    red[t] = v;
    __syncthreads();
    #pragma unroll
    for (int sft = 128; sft > 0; sft >>= 1) {
        if (t < sft) red[t] += red[t + sft];
        __syncthreads();
    }
    return red[0];
}

// Stage 1: q/k/v = manifold_linear(W,b,x); then fused logmap0 (512-dim) +
// expmap0 (flat 64-chunks, faithful to torch .view reshape). Writes ql/kl/vl
// into ws in flat [B,S,HID] (== [B,NH,S,HD]) layout. Also gamma for v chunks.
__global__ __launch_bounds__(256) void qkv_kernel(
    const float* __restrict__ query,
    const float* __restrict__ Wq, const float* __restrict__ bq,
    const float* __restrict__ Wk, const float* __restrict__ bk,
    const float* __restrict__ Wv, const float* __restrict__ bv,
    float* __restrict__ ws_qkv, float* __restrict__ ws_gamma)
{
    const int t = threadIdx.x;
    const int which = blockIdx.x >> 6;            // 0=q 1=k 2=v (64 blocks each)
    const int rowbase = (blockIdx.x & 63) * RPB_; // row = b*S + s, in [0,512)
    const float* __restrict__ W    = (which == 0) ? Wq : (which == 1) ? Wk : Wv;
    const float* __restrict__ bias = (which == 0) ? bq : (which == 1) ? bk : bv;
    float* __restrict__ outp = ws_qkv + (size_t)which * (B_ * S_ * HID_);

    __shared__ __align__(16) float sX[RPB_][HID_];
    __shared__ float red[256];
    __shared__ float red512[512];
    __shared__ float sb[HID_];
    __shared__ float scn[NH_];

    sb[t] = bias[t];
    sb[t + 256] = bias[t + 256];
    for (int r = 0; r < RPB_; ++r) {
        const int gr = rowbase + r;
        const int b = gr >> 8, s = gr & 255;
        // x = transpose(query,(1,0,2)) : x[b,s,:] = query[s,b,:]
        const float* src = query + (size_t)(s * B_ + b) * HID_;
        sX[r][t] = src[t];
        sX[r][t + 256] = src[t + 256];
    }
    __syncthreads();

    // mx[j] = sum_i x[i] * W[j,i] ; thread handles j = t and j = t+256
    float acc0[RPB_], acc1[RPB_];
    #pragma unroll
    for (int r = 0; r < RPB_; ++r) { acc0[r] = 0.f; acc1[r] = 0.f; }
    const float4* __restrict__ W4a = (const float4*)(W + (size_t)t * HID_);
    const float4* __restrict__ W4b = (const float4*)(W + (size_t)(t + 256) * HID_);
    #pragma unroll 4
    for (int i4 = 0; i4 < HID_ / 4; ++i4) {
        const float4 w0 = W4a[i4];
        const float4 w1 = W4b[i4];
        #pragma unroll
        for (int r = 0; r < RPB_; ++r) {
            const float4 xr = ((const float4*)sX[r])[i4];
            acc0[r] = fmaf(w0.x, xr.x, fmaf(w0.y, xr.y, fmaf(w0.z, xr.z, fmaf(w0.w, xr.w, acc0[r]))));
            acc1[r] = fmaf(w1.x, xr.x, fmaf(w1.y, xr.y, fmaf(w1.z, xr.z, fmaf(w1.w, xr.w, acc1[r]))));
        }
    }

    const float b0 = sb[t], b1 = sb[t + 256];
    const float b2s = block_sum_256(b0 * b0 + b1 * b1, red);  // ||bias||^2 (row-invariant)

    for (int r = 0; r < RPB_; ++r) {
        const float x0 = sX[r][t], x1 = sX[r][t + 256];
        const float m0 = acc0[r],  m1 = acc1[r];
        const float x2s = block_sum_256(x0 * x0 + x1 * x1, red);
        const float mn2 = block_sum_256(m0 * m0 + m1 * m1, red);
        const float xn = fmaxf(sqrtf(x2s), 1e-15f);
        const float mn = fmaxf(sqrtf(mn2), 1e-15f);
        // mobius_matvec: res = tanh(mn/xn * artanh(xn)) * mx/mn  (0 if mx==0)
        const float fac = tanhf(mn / xn * artanh_c(xn)) / mn;
        const float r0 = fac * m0, r1 = fac * m1;
        // mobius_add(res, bias)
        const float r2s = block_sum_256(r0 * r0 + r1 * r1, red);
        const float ry  = block_sum_256(r0 * b0 + r1 * b1, red);
        const float a_c = 1.f + 2.f * ry + b2s;
        const float b_c = 1.f - r2s;
        const float den = 1.f + 2.f * ry + r2s * b2s;
        const float inv_den = 1.f / fmaxf(den, 1e-15f);
        float h0 = (a_c * r0 + b_c * b0) * inv_den;
        float h1 = (a_c * r1 + b_c * b1) * inv_den;
        // projx: maxnorm = 1 - 4e-3
        const float h2s = block_sum_256(h0 * h0 + h1 * h1, red);
        float hn = fmaxf(sqrtf(h2s), 1e-15f);
        if (hn > 0.996f) { const float f = 0.996f / hn; h0 *= f; h1 *= f; hn = 0.996f; }
        // logmap0 over 512-dim row
        const float lf = artanh_c(hn) / hn;
        const float l0 = lf * h0, l1 = lf * h1;
        // expmap0 over flat 64-chunks (torch .view reshape semantics)
        __syncthreads();
        red512[t] = l0 * l0;
        red512[t + 256] = l1 * l1;
        __syncthreads();
        if (t < NH_) {
            float ssum = 0.f;
            #pragma unroll
            for (int d = 0; d < HD_; ++d) ssum += red512[t * HD_ + d];
            const float cn = fmaxf(sqrtf(ssum), 1e-15f);
            const float th = tanhf(cn);
            scn[t] = th / cn;
            if (which == 2) {
                // gamma = 2 / max(1 - ||vl_chunk||^2, eps); ||vl_chunk|| = tanh(cn)
                ws_gamma[(size_t)(rowbase + r) * NH_ + t] = 2.f / fmaxf(1.f - th * th, 1e-15f);
            }
        }
        __syncthreads();
        float* orow = outp + (size_t)(rowbase + r) * HID_;
        orow[t]       = scn[t >> 6] * l0;
        orow[t + 256] = scn[4 + (t >> 6)] * l1;
    }
}

// Stage 2: pairwise diff = mobius_add(-ql_q, kl_n); t1 = (sum 1/diff_d^2)^-1/2
// scores = clip(-2*artanh(t1)); probs = sigmoid. One thread per key n.
__global__ __launch_bounds__(256) void scores_kernel(
    const float* __restrict__ ws_qkv, float* __restrict__ probs)
{
    const int t = threadIdx.x;                 // n
    const int q = blockIdx.x & (S_ - 1);
    const int bh = blockIdx.x >> 8;            // b*NH + h, 0..15
    const float* __restrict__ ql = ws_qkv + (size_t)bh * S_ * HD_;
    const float* __restrict__ kl = ws_qkv + (size_t)B_ * S_ * HID_ + (size_t)bh * S_ * HD_;
    __shared__ float sq[HD_];
    if (t < HD_) sq[t] = ql[(size_t)q * HD_ + t];
    __syncthreads();
    const float* __restrict__ krow = kl + (size_t)t * HD_;
    float kr[HD_];
    float q2 = 0.f, k2 = 0.f, xy = 0.f;        // xy = dot(-q, k)
    #pragma unroll
    for (int d = 0; d < HD_; ++d) {
        const float kv = krow[d];
        const float qv = sq[d];
        kr[d] = kv;
        q2 = fmaf(qv, qv, q2);
        k2 = fmaf(kv, kv, k2);
        xy = fmaf(-qv, kv, xy);
    }
    const float a_c = 1.f + 2.f * xy + k2;     // multiplies x = -q
    const float b_c = 1.f - q2;                // multiplies y = k
    const float den = fmaxf(1.f + 2.f * xy + q2 * k2, 1e-15f);
    const float inv_den = 1.f / den;
    float invsum = 0.f;
    #pragma unroll
    for (int d = 0; d < HD_; ++d) {
        const float diff = (b_c * kr[d] - a_c * sq[d]) * inv_den;
        const float d2 = fmaxf(diff * diff, 1e-30f);
        invsum += __builtin_amdgcn_rcpf(d2);
    }
    const float t1 = __builtin_amdgcn_rsqf(invsum);
    float sc = -2.f * artanh_c(t1);
    sc = fminf(fmaxf(sc, -1e10f), 1e10f);
    const float p = 1.f / (1.f + __expf(-sc));
    probs[((size_t)(bh * S_ + q)) * S_ + t] = p;
}

// Stage 3: weighted gyro-midpoint + mobius_scalar_mul(0.5) + per-head logmap0.
// One wave (64 threads = d) per (b,h,q). lc layout: [B,NH,S,HD].
__global__ __launch_bounds__(64) void midpoint_kernel(
    const float* __restrict__ ws_qkv, const float* __restrict__ gamma,
    const float* __restrict__ probs, float* __restrict__ lc)
{
    const int d = threadIdx.x;
    const int q = blockIdx.x & (S_ - 1);
    const int bh = blockIdx.x >> 8;
    const float* __restrict__ vl   = ws_qkv + (size_t)2 * B_ * S_ * HID_ + (size_t)bh * S_ * HD_;
    const float* __restrict__ prow = probs + ((size_t)(bh * S_ + q)) * S_;
    const float* __restrict__ grow = gamma + (size_t)bh * S_;
    float nom = 0.f, dn = 0.f;
    #pragma unroll 4
    for (int n = 0; n < S_; ++n) {
        const float p = prow[n];
        const float g = grow[n];
        nom = fmaf(p * g, vl[(size_t)n * HD_ + d], nom);
        dn  = fmaf(p, g - 1.f, dn);
    }
    const float adn = fmaxf(fabsf(dn), 1e-10f);
    const float sden = (dn >= 0.f) ? adn : -adn;
    const float m = nom / sden;
    float ss = m * m;
    #pragma unroll
    for (int off = 32; off > 0; off >>= 1) ss += __shfl_xor(ss, off, 64);
    const float nn = fmaxf(sqrtf(ss), 1e-15f);
    const float s1 = tanhf(0.5f * artanh_c(nn));     // mobius_scalar_mul(0.5)
    const float res = s1 * m / nn;
    const float nres = fmaxf(s1, 1e-15f);            // ||res|| = s1 (s1 >= 0)
    const float l = (artanh_c(nres) / nres) * res;   // logmap0 over HD
    lc[((size_t)(bh * S_ + q)) * HD_ + d] = l;
}

// Stage 4: gather heads -> [B,Q,512] row, expmap0 over 512, store [S,B,HID].
__global__ __launch_bounds__(256) void outproj_kernel(
    const float* __restrict__ lc, float* __restrict__ out0)
{
    const int t = threadIdx.x;
    const int s = blockIdx.x & (S_ - 1);
    const int b = blockIdx.x >> 8;
    __shared__ float red[256];
    const int h0 = t >> 6, d0 = t & 63;
    const int e1 = t + 256;
    const int h1 = e1 >> 6, d1 = e1 & 63;
    const float v0 = lc[(((size_t)(b * NH_ + h0)) * S_ + s) * HD_ + d0];
    const float v1 = lc[(((size_t)(b * NH_ + h1)) * S_ + s) * HD_ + d1];
    const float ss = block_sum_256(v0 * v0 + v1 * v1, red);
    const float nn = fmaxf(sqrtf(ss), 1e-15f);
    const float f = tanhf(nn) / nn;
    float* orow = out0 + ((size_t)(s * B_ + b)) * HID_;
    orow[t] = f * v0;
    orow[t + 256] = f * v1;
}

extern "C" void kernel_launch(void* const* d_in, const int* in_sizes, int n_in,
                              void* d_out, int out_size, void* d_ws, size_t ws_size,
                              hipStream_t stream) {
    (void)in_sizes; (void)n_in; (void)out_size; (void)ws_size;
    const float* query = (const float*)d_in[0];
    const float* Wq = (const float*)d_in[1];
    const float* bq = (const float*)d_in[2];
    const float* Wk = (const float*)d_in[3];
    const float* bk = (const float*)d_in[4];
    const float* Wv = (const float*)d_in[5];
    const float* bv = (const float*)d_in[6];

    float* out0  = (float*)d_out;                          // [S,B,HID] = 262144
    float* probs = out0 + (size_t)S_ * B_ * HID_;          // [B,NH,S,S] = 1048576

    float* ws       = (float*)d_ws;
    float* ws_qkv   = ws;                                  // ql|kl|vl : 3*262144 floats
    float* ws_gamma = ws + (size_t)3 * B_ * S_ * HID_;     // 4096 floats
    float* ws_lc    = ws_qkv;                              // alias ql (dead after scores)

    qkv_kernel<<<dim3(3 * (B_ * S_ / RPB_)), dim3(256), 0, stream>>>(
        query, Wq, bq, Wk, bk, Wv, bv, ws_qkv, ws_gamma);
    scores_kernel<<<dim3(B_ * NH_ * S_), dim3(256), 0, stream>>>(ws_qkv, probs);
    midpoint_kernel<<<dim3(B_ * NH_ * S_), dim3(64), 0, stream>>>(
        ws_qkv, ws_gamma, probs, ws_lc);
    outproj_kernel<<<dim3(B_ * S_), dim3(256), 0, stream>>>(ws_lc, out0);
}

// Round 2
// 159.822 us; speedup vs baseline: 1.4380x; 1.4380x over previous
//
#include <hip/hip_runtime.h>
#include <math.h>

// Problem constants (reference: S=256, B=2, HID=512, NH=8, HD=64, C=1)
constexpr int S_   = 256;
constexpr int B_   = 2;
constexpr int HID_ = 512;
constexpr int NH_  = 8;
constexpr int HD_  = 64;
constexpr int BSH  = B_ * S_ * HID_;   // 262144

__device__ __forceinline__ float artanh_c(float x) {
    // reference _artanh: clip to [-1+1e-7, 1-1e-7], then artanh
    x = fminf(fmaxf(x, -0.9999999f), 0.9999999f);
    return 0.5f * __logf((1.f + x) / (1.f - x));
}

__device__ __forceinline__ float wsum64(float v) {
    #pragma unroll
    for (int o = 1; o < 64; o <<= 1) v += __shfl_xor(v, o, 64);
    return v;
}

__device__ __forceinline__ float block_sum_256(float v, float* red) {
    const int t = threadIdx.x;
    __syncthreads();              // protect previous use of red
    red[t] = v;
    __syncthreads();
    #pragma unroll
    for (int sft = 128; sft > 0; sft >>= 1) {
        if (t < sft) red[t] += red[t + sft];
        __syncthreads();
    }
    return red[0];
}

// ---------------------------------------------------------------------------
// Stage 1a: mx = x @ W^T for all three weight matrices, as a tiled fp32 GEMM.
// x[row=b*S+s, i] = query[s*B+b, i]. Output ws_mx[which][row][col].
// Tiles: TM=32 rows x TN=64 cols, KC=32. Grid: 3 * 16 * 8 = 384 blocks.
// ---------------------------------------------------------------------------
constexpr int TM_ = 32, TN_ = 64, KC_ = 32;

__global__ __launch_bounds__(256) void gemm3_kernel(
    const float* __restrict__ query,
    const float* __restrict__ Wq, const float* __restrict__ Wk,
    const float* __restrict__ Wv, float* __restrict__ ws_mx)
{
    const int tid   = threadIdx.x;
    const int which = blockIdx.x >> 7;      // 128 tiles per matrix
    const int tmp   = blockIdx.x & 127;
    const int row0  = (tmp >> 3) * TM_;
    const int col0  = (tmp & 7) * TN_;
    const float* __restrict__ W = (which == 0) ? Wq : (which == 1) ? Wk : Wv;
    float* __restrict__ outp = ws_mx + (size_t)which * (HID_ * HID_);

    __shared__ __align__(16) float sA[KC_][68];   // [kk][row], padded
    __shared__ __align__(16) float sB[KC_][68];   // [kk][col], padded

    const int sr = tid >> 3;          // 0..31
    const int sk = (tid & 7) * 4;     // 0,4,...,28
    const int gra = row0 + sr;        // global x row (b*S+s)
    const float* pa  = query + (size_t)((gra & 255) * 2 + (gra >> 8)) * HID_ + sk;
    const float* pb0 = W + (size_t)(col0 + sr) * HID_ + sk;
    const float* pb1 = W + (size_t)(col0 + sr + 32) * HID_ + sk;

    const int ty = tid >> 4, tx = tid & 15;   // thread tile: rows ty*2+{0,1}, cols tx*4+{0..3}
    float acc[2][4] = {};

    float4 va  = *(const float4*)pa;
    float4 vb0 = *(const float4*)pb0;
    float4 vb1 = *(const float4*)pb1;
    for (int k0 = 0; k0 < HID_; k0 += KC_) {
        __syncthreads();
        sA[sk+0][sr] = va.x;  sA[sk+1][sr] = va.y;  sA[sk+2][sr] = va.z;  sA[sk+3][sr] = va.w;
        sB[sk+0][sr] = vb0.x; sB[sk+1][sr] = vb0.y; sB[sk+2][sr] = vb0.z; sB[sk+3][sr] = vb0.w;
        sB[sk+0][sr+32] = vb1.x; sB[sk+1][sr+32] = vb1.y; sB[sk+2][sr+32] = vb1.z; sB[sk+3][sr+32] = vb1.w;
        __syncthreads();
        if (k0 + KC_ < HID_) {            // prefetch next chunk, overlaps compute
            va  = *(const float4*)(pa + k0 + KC_);
            vb0 = *(const float4*)(pb0 + k0 + KC_);
            vb1 = *(const float4*)(pb1 + k0 + KC_);
        }
        #pragma unroll
        for (int kk = 0; kk < KC_; ++kk) {
            const float2 av = *(const float2*)&sA[kk][ty * 2];
            const float4 bv = *(const float4*)&sB[kk][tx * 4];
            acc[0][0] = fmaf(av.x, bv.x, acc[0][0]);
            acc[0][1] = fmaf(av.x, bv.y, acc[0][1]);
            acc[0][2] = fmaf(av.x, bv.z, acc[0][2]);
            acc[0][3] = fmaf(av.x, bv.w, acc[0][3]);
            acc[1][0] = fmaf(av.y, bv.x, acc[1][0]);
            acc[1][1] = fmaf(av.y, bv.y, acc[1][1]);
            acc[1][2] = fmaf(av.y, bv.z, acc[1][2]);
            acc[1][3] = fmaf(av.y, bv.w, acc[1][3]);
        }
    }
    #pragma unroll
    for (int i = 0; i < 2; ++i) {
        float4 o = make_float4(acc[i][0], acc[i][1], acc[i][2], acc[i][3]);
        *(float4*)&outp[(size_t)(row0 + ty * 2 + i) * HID_ + col0 + tx * 4] = o;
    }
}

// ---------------------------------------------------------------------------
// Stage 1b: per-row mobius epilogue, ONE WAVE PER ROW (no barriers).
// In-place: reads mx row from ws_qkv, writes q/k/v (logmap0+chunk expmap0).
// Also writes gamma for v in [b][h][s] layout. Grid: 1536/4 = 384 blocks.
// ---------------------------------------------------------------------------
__global__ __launch_bounds__(256) void mobius_rows_kernel(
    const float* __restrict__ query,
    const float* __restrict__ bq, const float* __restrict__ bk,
    const float* __restrict__ bv,
    float* __restrict__ ws_qkv, float* __restrict__ ws_gamma)
{
    const int lane = threadIdx.x & 63;
    const int wv   = threadIdx.x >> 6;
    const int row  = blockIdx.x * 4 + wv;     // 0..1535
    const int which = row >> 9;
    const int rr    = row & 511;              // b*S + s
    const float* __restrict__ bias = (which == 0) ? bq : (which == 1) ? bk : bv;
    float* mrow = ws_qkv + (size_t)row * HID_;           // which*BSH/... == row*512
    const float* xrow = query + (size_t)((rr & 255) * 2 + (rr >> 8)) * HID_;

    float m[8], x[8], bb[8];
    *(float4*)&m[0]  = ((const float4*)mrow)[lane * 2];
    *(float4*)&m[4]  = ((const float4*)mrow)[lane * 2 + 1];
    *(float4*)&x[0]  = ((const float4*)xrow)[lane * 2];
    *(float4*)&x[4]  = ((const float4*)xrow)[lane * 2 + 1];
    *(float4*)&bb[0] = ((const float4*)bias)[lane * 2];
    *(float4*)&bb[4] = ((const float4*)bias)[lane * 2 + 1];

    float x2p = 0.f, m2p = 0.f, b2p = 0.f;
    #pragma unroll
    for (int j = 0; j < 8; ++j) {
        x2p = fmaf(x[j], x[j], x2p);
        m2p = fmaf(m[j], m[j], m2p);
        b2p = fmaf(bb[j], bb[j], b2p);
    }
    const float x2s = wsum64(x2p);
    const float mn2 = wsum64(m2p);
    const float b2s = wsum64(b2p);
    const float xn = fmaxf(sqrtf(x2s), 1e-15f);
    const float mn = fmaxf(sqrtf(mn2), 1e-15f);
    // mobius_matvec: res = tanh(mn/xn * artanh(xn)) * mx/mn
    const float fac = tanhf(mn / xn * artanh_c(xn)) / mn;
    float r[8];
    float r2p = 0.f, ryp = 0.f;
    #pragma unroll
    for (int j = 0; j < 8; ++j) {
        r[j] = fac * m[j];
        r2p = fmaf(r[j], r[j], r2p);
        ryp = fmaf(r[j], bb[j], ryp);
    }
    const float r2s = wsum64(r2p);
    const float ry  = wsum64(ryp);
    // mobius_add(r, bias)
    const float a_c = 1.f + 2.f * ry + b2s;
    const float b_c = 1.f - r2s;
    const float den = 1.f + 2.f * ry + r2s * b2s;
    const float inv_den = 1.f / fmaxf(den, 1e-15f);
    float h[8];
    float h2p = 0.f;
    #pragma unroll
    for (int j = 0; j < 8; ++j) {
        h[j] = (a_c * r[j] + b_c * bb[j]) * inv_den;
        h2p = fmaf(h[j], h[j], h2p);
    }
    const float h2s = wsum64(h2p);
    float hn = fmaxf(sqrtf(h2s), 1e-15f);
    float pf = 1.f;
    if (hn > 0.996f) { pf = 0.996f / hn; hn = 0.996f; }   // projx
    const float lf = artanh_c(hn) / hn * pf;               // logmap0 (512-dim)
    float l[8];
    float l2p = 0.f;
    #pragma unroll
    for (int j = 0; j < 8; ++j) {
        l[j] = lf * h[j];
        l2p = fmaf(l[j], l[j], l2p);
    }
    // expmap0 over flat 64-chunks: chunk h = lanes h*8 .. h*8+7
    float cs = l2p;
    cs += __shfl_xor(cs, 1, 64);
    cs += __shfl_xor(cs, 2, 64);
    cs += __shfl_xor(cs, 4, 64);
    const float cn = fmaxf(sqrtf(cs), 1e-15f);
    const float th = tanhf(cn);
    const float sc = th / cn;
    float o[8];
    #pragma unroll
    for (int j = 0; j < 8; ++j) o[j] = sc * l[j];
    ((float4*)mrow)[lane * 2]     = *(float4*)&o[0];
    ((float4*)mrow)[lane * 2 + 1] = *(float4*)&o[4];
    if (which == 2 && (lane & 7) == 0) {
        const int hh = lane >> 3, b = rr >> 8, s = rr & 255;
        // gamma = 2 / max(1 - ||vl_chunk||^2, eps); ||vl_chunk|| = tanh(cn)
        ws_gamma[((size_t)(b * NH_ + hh)) * S_ + s] = 2.f / fmaxf(1.f - th * th, 1e-15f);
    }
}

// ---------------------------------------------------------------------------
// Stage 2: pairwise diff = mobius_add(-ql_q, kl_n); t1 = (sum 1/diff_d^2)^-1/2
// scores = clip(-2*artanh(t1)); probs = sigmoid. One thread per key n.
// ---------------------------------------------------------------------------
__global__ __launch_bounds__(256) void scores_kernel(
    const float* __restrict__ ws_qkv, float* __restrict__ probs)
{
    const int t = threadIdx.x;                 // n
    const int q = blockIdx.x & (S_ - 1);
    const int bh = blockIdx.x >> 8;            // b*NH + h, 0..15
    const float* __restrict__ ql = ws_qkv + (size_t)bh * S_ * HD_;
    const float* __restrict__ kl = ws_qkv + (size_t)BSH + (size_t)bh * S_ * HD_;
    __shared__ float sq[HD_];
    if (t < HD_) sq[t] = ql[(size_t)q * HD_ + t];
    __syncthreads();
    const float* __restrict__ krow = kl + (size_t)t * HD_;
    float kr[HD_];
    float q2 = 0.f, k2 = 0.f, xy = 0.f;        // xy = dot(-q, k)
    #pragma unroll
    for (int d = 0; d < HD_; ++d) {
        const float kv = krow[d];
        const float qv = sq[d];
        kr[d] = kv;
        q2 = fmaf(qv, qv, q2);
        k2 = fmaf(kv, kv, k2);
        xy = fmaf(-qv, kv, xy);
    }
    const float a_c = 1.f + 2.f * xy + k2;     // multiplies x = -q
    const float b_c = 1.f - q2;                // multiplies y = k
    const float den = fmaxf(1.f + 2.f * xy + q2 * k2, 1e-15f);
    const float inv_den = 1.f / den;
    float invsum = 0.f;
    #pragma unroll
    for (int d = 0; d < HD_; ++d) {
        const float diff = (b_c * kr[d] - a_c * sq[d]) * inv_den;
        const float d2 = fmaxf(diff * diff, 1e-30f);
        invsum += __builtin_amdgcn_rcpf(d2);
    }
    const float t1 = __builtin_amdgcn_rsqf(invsum);
    float sc = -2.f * artanh_c(t1);
    sc = fminf(fmaxf(sc, -1e10f), 1e10f);
    const float p = 1.f / (1.f + __expf(-sc));
    probs[((size_t)(bh * S_ + q)) * S_ + t] = p;
}

// ---------------------------------------------------------------------------
// Stage 3: weighted gyro-midpoint + mobius_scalar_mul(0.5) + per-head logmap0.
// 4 waves per (b,h,q): n-loop split across waves, combined via LDS.
// ---------------------------------------------------------------------------
__global__ __launch_bounds__(256) void midpoint_kernel(
    const float* __restrict__ ws_qkv, const float* __restrict__ gamma,
    const float* __restrict__ probs, float* __restrict__ lc)
{
    const int tid  = threadIdx.x;
    const int lane = tid & 63, wv = tid >> 6;
    const int q  = blockIdx.x & (S_ - 1);
    const int bh = blockIdx.x >> 8;
    const float* __restrict__ vl   = ws_qkv + (size_t)2 * BSH + (size_t)bh * S_ * HD_;
    const float* __restrict__ prow = probs + ((size_t)(bh * S_ + q)) * S_;
    const float* __restrict__ grow = gamma + (size_t)bh * S_;
    float nom = 0.f, dn = 0.f;
    #pragma unroll 8
    for (int i = 0; i < 64; ++i) {
        const int n = wv * 64 + i;
        const float p = prow[n];
        const float g = grow[n];
        nom = fmaf(p * g, vl[(size_t)n * HD_ + lane], nom);
        dn  = fmaf(p, g - 1.f, dn);
    }
    __shared__ float nomP[4][64];
    __shared__ float dnP[4];
    nomP[wv][lane] = nom;
    if (lane == 0) dnP[wv] = dn;
    __syncthreads();
    if (tid < 64) {
        const float nm = nomP[0][tid] + nomP[1][tid] + nomP[2][tid] + nomP[3][tid];
        const float dd = dnP[0] + dnP[1] + dnP[2] + dnP[3];
        const float adn = fmaxf(fabsf(dd), 1e-10f);
        const float sden = (dd >= 0.f) ? adn : -adn;
        const float m = nm / sden;
        float ss = wsum64(m * m);
        const float nn = fmaxf(sqrtf(ss), 1e-15f);
        const float s1 = tanhf(0.5f * artanh_c(nn));     // mobius_scalar_mul(0.5)
        const float res = s1 * m / nn;
        const float nres = fmaxf(s1, 1e-15f);            // ||res|| = s1 (s1 >= 0)
        const float l = (artanh_c(nres) / nres) * res;   // logmap0 over HD
        lc[((size_t)(bh * S_ + q)) * HD_ + tid] = l;
    }
}

// ---------------------------------------------------------------------------
// Stage 4: gather heads -> [B,Q,512] row, expmap0 over 512, store [S,B,HID].
// ---------------------------------------------------------------------------
__global__ __launch_bounds__(256) void outproj_kernel(
    const float* __restrict__ lc, float* __restrict__ out0)
{
    const int t = threadIdx.x;
    const int s = blockIdx.x & (S_ - 1);
    const int b = blockIdx.x >> 8;
    __shared__ float red[256];
    const int h0 = t >> 6, d0 = t & 63;
    const int e1 = t + 256;
    const int h1 = e1 >> 6, d1 = e1 & 63;
    const float v0 = lc[(((size_t)(b * NH_ + h0)) * S_ + s) * HD_ + d0];
    const float v1 = lc[(((size_t)(b * NH_ + h1)) * S_ + s) * HD_ + d1];
    const float ss = block_sum_256(v0 * v0 + v1 * v1, red);
    const float nn = fmaxf(sqrtf(ss), 1e-15f);
    const float f = tanhf(nn) / nn;
    float* orow = out0 + ((size_t)(s * B_ + b)) * HID_;
    orow[t] = f * v0;
    orow[t + 256] = f * v1;
}

extern "C" void kernel_launch(void* const* d_in, const int* in_sizes, int n_in,
                              void* d_out, int out_size, void* d_ws, size_t ws_size,
                              hipStream_t stream) {
    (void)in_sizes; (void)n_in; (void)out_size; (void)ws_size;
    const float* query = (const float*)d_in[0];
    const float* Wq = (const float*)d_in[1];
    const float* bq = (const float*)d_in[2];
    const float* Wk = (const float*)d_in[3];
    const float* bk = (const float*)d_in[4];
    const float* Wv = (const float*)d_in[5];
    const float* bv = (const float*)d_in[6];

    float* out0  = (float*)d_out;                          // [S,B,HID] = 262144
    float* probs = out0 + (size_t)S_ * B_ * HID_;          // [B,NH,S,S] = 1048576

    float* ws       = (float*)d_ws;
    float* ws_qkv   = ws;                                  // mx -> ql|kl|vl : 3*262144 floats
    float* ws_gamma = ws + (size_t)3 * BSH;                // 4096 floats, [b][h][s]
    float* ws_lc    = ws_qkv;                              // alias ql (dead after scores)

    gemm3_kernel<<<dim3(3 * 128), dim3(256), 0, stream>>>(query, Wq, Wk, Wv, ws_qkv);
    mobius_rows_kernel<<<dim3(384), dim3(256), 0, stream>>>(query, bq, bk, bv, ws_qkv, ws_gamma);
    scores_kernel<<<dim3(B_ * NH_ * S_), dim3(256), 0, stream>>>(ws_qkv, probs);
    midpoint_kernel<<<dim3(B_ * NH_ * S_), dim3(256), 0, stream>>>(ws_qkv, ws_gamma, probs, ws_lc);
    outproj_kernel<<<dim3(B_ * S_), dim3(256), 0, stream>>>(ws_lc, out0);
}

// Round 3
// 143.594 us; speedup vs baseline: 1.6005x; 1.1130x over previous
//
#include <hip/hip_runtime.h>
#include <math.h>

// Problem constants (reference: S=256, B=2, HID=512, NH=8, HD=64, C=1)
constexpr int S_   = 256;
constexpr int B_   = 2;
constexpr int HID_ = 512;
constexpr int NH_  = 8;
constexpr int HD_  = 64;
constexpr int BSH  = B_ * S_ * HID_;   // 262144

__device__ __forceinline__ float artanh_c(float x) {
    // reference _artanh: clip to [-1+1e-7, 1-1e-7], then artanh
    x = fminf(fmaxf(x, -0.9999999f), 0.9999999f);
    return 0.5f * __logf((1.f + x) / (1.f - x));
}

__device__ __forceinline__ float wsum64(float v) {
    #pragma unroll
    for (int o = 1; o < 64; o <<= 1) v += __shfl_xor(v, o, 64);
    return v;
}

__device__ __forceinline__ float block_sum_256(float v, float* red) {
    const int t = threadIdx.x;
    __syncthreads();              // protect previous use of red
    red[t] = v;
    __syncthreads();
    #pragma unroll
    for (int sft = 128; sft > 0; sft >>= 1) {
        if (t < sft) red[t] += red[t + sft];
        __syncthreads();
    }
    return red[0];
}

// ---------------------------------------------------------------------------
// Stage 1a: mx = x @ W^T for all three weight matrices, as a tiled fp32 GEMM.
// x[row=b*S+s, i] = query[s*B+b, i]. Output ws_mx[which][row][col].
// Tiles: TM=32 rows x TN=64 cols, KC=32. Grid: 3 * 16 * 8 = 384 blocks.
// ---------------------------------------------------------------------------
constexpr int TM_ = 32, TN_ = 64, KC_ = 32;

__global__ __launch_bounds__(256) void gemm3_kernel(
    const float* __restrict__ query,
    const float* __restrict__ Wq, const float* __restrict__ Wk,
    const float* __restrict__ Wv, float* __restrict__ ws_mx)
{
    const int tid   = threadIdx.x;
    const int which = blockIdx.x >> 7;      // 128 tiles per matrix
    const int tmp   = blockIdx.x & 127;
    const int row0  = (tmp >> 3) * TM_;
    const int col0  = (tmp & 7) * TN_;
    const float* __restrict__ W = (which == 0) ? Wq : (which == 1) ? Wk : Wv;
    float* __restrict__ outp = ws_mx + (size_t)which * (HID_ * HID_);

    __shared__ __align__(16) float sA[KC_][68];   // [kk][row], padded
    __shared__ __align__(16) float sB[KC_][68];   // [kk][col], padded

    const int sr = tid >> 3;          // 0..31
    const int sk = (tid & 7) * 4;     // 0,4,...,28
    const int gra = row0 + sr;        // global x row (b*S+s)
    const float* pa  = query + (size_t)((gra & 255) * 2 + (gra >> 8)) * HID_ + sk;
    const float* pb0 = W + (size_t)(col0 + sr) * HID_ + sk;
    const float* pb1 = W + (size_t)(col0 + sr + 32) * HID_ + sk;

    const int ty = tid >> 4, tx = tid & 15;   // thread tile: rows ty*2+{0,1}, cols tx*4+{0..3}
    float acc[2][4] = {};

    float4 va  = *(const float4*)pa;
    float4 vb0 = *(const float4*)pb0;
    float4 vb1 = *(const float4*)pb1;
    for (int k0 = 0; k0 < HID_; k0 += KC_) {
        __syncthreads();
        sA[sk+0][sr] = va.x;  sA[sk+1][sr] = va.y;  sA[sk+2][sr] = va.z;  sA[sk+3][sr] = va.w;
        sB[sk+0][sr] = vb0.x; sB[sk+1][sr] = vb0.y; sB[sk+2][sr] = vb0.z; sB[sk+3][sr] = vb0.w;
        sB[sk+0][sr+32] = vb1.x; sB[sk+1][sr+32] = vb1.y; sB[sk+2][sr+32] = vb1.z; sB[sk+3][sr+32] = vb1.w;
        __syncthreads();
        if (k0 + KC_ < HID_) {            // prefetch next chunk, overlaps compute
            va  = *(const float4*)(pa + k0 + KC_);
            vb0 = *(const float4*)(pb0 + k0 + KC_);
            vb1 = *(const float4*)(pb1 + k0 + KC_);
        }
        #pragma unroll
        for (int kk = 0; kk < KC_; ++kk) {
            const float2 av = *(const float2*)&sA[kk][ty * 2];
            const float4 bv = *(const float4*)&sB[kk][tx * 4];
            acc[0][0] = fmaf(av.x, bv.x, acc[0][0]);
            acc[0][1] = fmaf(av.x, bv.y, acc[0][1]);
            acc[0][2] = fmaf(av.x, bv.z, acc[0][2]);
            acc[0][3] = fmaf(av.x, bv.w, acc[0][3]);
            acc[1][0] = fmaf(av.y, bv.x, acc[1][0]);
            acc[1][1] = fmaf(av.y, bv.y, acc[1][1]);
            acc[1][2] = fmaf(av.y, bv.z, acc[1][2]);
            acc[1][3] = fmaf(av.y, bv.w, acc[1][3]);
        }
    }
    #pragma unroll
    for (int i = 0; i < 2; ++i) {
        float4 o = make_float4(acc[i][0], acc[i][1], acc[i][2], acc[i][3]);
        *(float4*)&outp[(size_t)(row0 + ty * 2 + i) * HID_ + col0 + tx * 4] = o;
    }
}

// ---------------------------------------------------------------------------
// Stage 1b: per-row mobius epilogue, ONE WAVE PER ROW (no barriers).
// In-place: reads mx row from ws_qkv, writes q/k/v (logmap0+chunk expmap0).
// gamma stored in FLAT CHUNK ORDER: index = (b*S+s)*NH + hh  (== b,h*S+n when
// read as [b][h][n] through the reshape identity). Grid: 1536/4 = 384 blocks.
// ---------------------------------------------------------------------------
__global__ __launch_bounds__(256) void mobius_rows_kernel(
    const float* __restrict__ query,
    const float* __restrict__ bq, const float* __restrict__ bk,
    const float* __restrict__ bv,
    float* __restrict__ ws_qkv, float* __restrict__ ws_gamma)
{
    const int lane = threadIdx.x & 63;
    const int wv   = threadIdx.x >> 6;
    const int row  = blockIdx.x * 4 + wv;     // 0..1535
    const int which = row >> 9;
    const int rr    = row & 511;              // b*S + s
    const float* __restrict__ bias = (which == 0) ? bq : (which == 1) ? bk : bv;
    float* mrow = ws_qkv + (size_t)row * HID_;
    const float* xrow = query + (size_t)((rr & 255) * 2 + (rr >> 8)) * HID_;

    float m[8], x[8], bb[8];
    *(float4*)&m[0]  = ((const float4*)mrow)[lane * 2];
    *(float4*)&m[4]  = ((const float4*)mrow)[lane * 2 + 1];
    *(float4*)&x[0]  = ((const float4*)xrow)[lane * 2];
    *(float4*)&x[4]  = ((const float4*)xrow)[lane * 2 + 1];
    *(float4*)&bb[0] = ((const float4*)bias)[lane * 2];
    *(float4*)&bb[4] = ((const float4*)bias)[lane * 2 + 1];

    float x2p = 0.f, m2p = 0.f, b2p = 0.f;
    #pragma unroll
    for (int j = 0; j < 8; ++j) {
        x2p = fmaf(x[j], x[j], x2p);
        m2p = fmaf(m[j], m[j], m2p);
        b2p = fmaf(bb[j], bb[j], b2p);
    }
    const float x2s = wsum64(x2p);
    const float mn2 = wsum64(m2p);
    const float b2s = wsum64(b2p);
    const float xn = fmaxf(sqrtf(x2s), 1e-15f);
    const float mn = fmaxf(sqrtf(mn2), 1e-15f);
    // mobius_matvec: res = tanh(mn/xn * artanh(xn)) * mx/mn
    const float fac = tanhf(mn / xn * artanh_c(xn)) / mn;
    float r[8];
    float r2p = 0.f, ryp = 0.f;
    #pragma unroll
    for (int j = 0; j < 8; ++j) {
        r[j] = fac * m[j];
        r2p = fmaf(r[j], r[j], r2p);
        ryp = fmaf(r[j], bb[j], ryp);
    }
    const float r2s = wsum64(r2p);
    const float ry  = wsum64(ryp);
    // mobius_add(r, bias)
    const float a_c = 1.f + 2.f * ry + b2s;
    const float b_c = 1.f - r2s;
    const float den = 1.f + 2.f * ry + r2s * b2s;
    const float inv_den = 1.f / fmaxf(den, 1e-15f);
    float h[8];
    float h2p = 0.f;
    #pragma unroll
    for (int j = 0; j < 8; ++j) {
        h[j] = (a_c * r[j] + b_c * bb[j]) * inv_den;
        h2p = fmaf(h[j], h[j], h2p);
    }
    const float h2s = wsum64(h2p);
    float hn = fmaxf(sqrtf(h2s), 1e-15f);
    float pf = 1.f;
    if (hn > 0.996f) { pf = 0.996f / hn; hn = 0.996f; }   // projx
    const float lf = artanh_c(hn) / hn * pf;               // logmap0 (512-dim)
    float l[8];
    float l2p = 0.f;
    #pragma unroll
    for (int j = 0; j < 8; ++j) {
        l[j] = lf * h[j];
        l2p = fmaf(l[j], l[j], l2p);
    }
    // expmap0 over flat 64-chunks: chunk hh = lanes hh*8 .. hh*8+7
    float cs = l2p;
    cs += __shfl_xor(cs, 1, 64);
    cs += __shfl_xor(cs, 2, 64);
    cs += __shfl_xor(cs, 4, 64);
    const float cn = fmaxf(sqrtf(cs), 1e-15f);
    const float th = tanhf(cn);
    const float sc = th / cn;
    float o[8];
    #pragma unroll
    for (int j = 0; j < 8; ++j) o[j] = sc * l[j];
    ((float4*)mrow)[lane * 2]     = *(float4*)&o[0];
    ((float4*)mrow)[lane * 2 + 1] = *(float4*)&o[4];
    if (which == 2 && (lane & 7) == 0) {
        const int hh = lane >> 3;
        // gamma = 2 / max(1 - ||vl_chunk||^2, eps); ||vl_chunk|| = tanh(cn)
        // FLAT CHUNK ORDER: (b*S+s)*NH + hh
        ws_gamma[(size_t)rr * NH_ + hh] = 2.f / fmaxf(1.f - th * th, 1e-15f);
    }
}

// ---------------------------------------------------------------------------
// Stage 2: probs[bh][q][n]. Algebraic simplifications (exact):
//   diff_d = (b_c*k_d - a_c*q_d)/den,  b_c=1-|q|^2, a_c=1-2s+|k|^2,
//   den=max(1-2s+|q|^2|k|^2,1e-15), s=<q,k>
//   sum_d 1/max(diff_d^2,1e-30) = den^2 * sum_d 1/(u_d^2 + 1e-30*den^2)
//   sigmoid(clip(-2*artanh(clip(t1)))) == (1 - min(t1, 1-1e-7))/2
// Block: 8 q-rows x 256 n; K staged in two 128-row LDS halves (XOR-swizzled).
// Grid: 16 bh * 32 qtiles = 512 blocks.
// ---------------------------------------------------------------------------
__global__ __launch_bounds__(256) void scores_kernel(
    const float* __restrict__ ws_qkv, float* __restrict__ probs)
{
    const int tid = threadIdx.x;
    const int bh  = blockIdx.x >> 5;
    const int q0  = (blockIdx.x & 31) * 8;
    const float* __restrict__ ql = ws_qkv + (size_t)bh * (S_ * HD_);
    const float* __restrict__ kl = ws_qkv + (size_t)BSH + (size_t)bh * (S_ * HD_);

    __shared__ __align__(16) float kS[128 * 64];   // 32 KB, swizzled
    __shared__ __align__(16) float qS[8 * 64];     // 2 KB

    if (tid < 128) ((float4*)qS)[tid] = ((const float4*)(ql + (size_t)q0 * 64))[tid];
    __syncthreads();

    const int q_l = tid >> 5;       // 0..7
    const int n_i = tid & 31;       // 0..31
    float qv[64];
    #pragma unroll
    for (int c = 0; c < 16; ++c)
        *(float4*)&qv[c * 4] = *(const float4*)&qS[q_l * 64 + c * 4];
    float q2 = 0.f;
    #pragma unroll
    for (int d = 0; d < 64; ++d) q2 = fmaf(qv[d], qv[d], q2);
    const float b_c = 1.f - q2;
    float* __restrict__ prow = probs + ((size_t)(bh * S_ + q0 + q_l)) * S_;

    const int c4 = tid & 15;        // staging: chunk
    const int nb = tid >> 4;        // staging: row base

    for (int half = 0; half < 2; ++half) {
        __syncthreads();            // protect kS reuse across halves
        #pragma unroll
        for (int jj = 0; jj < 8; ++jj) {
            const int n = nb + 16 * jj;   // 0..127
            const float4 v = *(const float4*)(kl + ((size_t)(half * 128 + n)) * 64 + c4 * 4);
            *(float4*)&kS[n * 64 + ((c4 ^ (n & 15)) * 4)] = v;
        }
        __syncthreads();
        #pragma unroll
        for (int j = 0; j < 4; ++j) {
            const int n = n_i + 32 * j;   // within half
            float kv[64];
            #pragma unroll
            for (int c = 0; c < 16; ++c)
                *(float4*)&kv[c * 4] = *(const float4*)&kS[n * 64 + ((c ^ (n & 15)) * 4)];
            float s = 0.f, k2 = 0.f;
            #pragma unroll
            for (int d = 0; d < 64; ++d) {
                s  = fmaf(qv[d], kv[d], s);
                k2 = fmaf(kv[d], kv[d], k2);
            }
            const float a_c = 1.f - 2.f * s + k2;
            const float den = fmaxf(fmaf(q2, k2, 1.f - 2.f * s), 1e-15f);
            const float c2  = 1e-30f * den * den;
            float invsum = 0.f;
            #pragma unroll
            for (int d = 0; d < 64; ++d) {
                const float u = fmaf(b_c, kv[d], -(a_c * qv[d]));
                invsum += __builtin_amdgcn_rcpf(fmaf(u, u, c2));
            }
            const float t1 = __builtin_amdgcn_rsqf(den * den * invsum);
            prow[half * 128 + n] = 0.5f - 0.5f * fminf(t1, 0.9999999f);
        }
    }
}

// ---------------------------------------------------------------------------
// Stage 3: weighted gyro-midpoint + mobius_scalar_mul(0.5) + per-head logmap0.
// 4 waves per (b,h,q): n-loop split across waves, combined via LDS.
// ---------------------------------------------------------------------------
__global__ __launch_bounds__(256) void midpoint_kernel(
    const float* __restrict__ ws_qkv, const float* __restrict__ gamma,
    const float* __restrict__ probs, float* __restrict__ lc)
{
    const int tid  = threadIdx.x;
    const int lane = tid & 63, wv = tid >> 6;
    const int q  = blockIdx.x & (S_ - 1);
    const int bh = blockIdx.x >> 8;
    const float* __restrict__ vl   = ws_qkv + (size_t)2 * BSH + (size_t)bh * S_ * HD_;
    const float* __restrict__ prow = probs + ((size_t)(bh * S_ + q)) * S_;
    const float* __restrict__ grow = gamma + (size_t)bh * S_;  // flat chunk order
    float nom = 0.f, dn = 0.f;
    #pragma unroll 8
    for (int i = 0; i < 64; ++i) {
        const int n = wv * 64 + i;
        const float p = prow[n];
        const float g = grow[n];
        nom = fmaf(p * g, vl[(size_t)n * HD_ + lane], nom);
        dn  = fmaf(p, g - 1.f, dn);
    }
    __shared__ float nomP[4][64];
    __shared__ float dnP[4];
    nomP[wv][lane] = nom;
    if (lane == 0) dnP[wv] = dn;
    __syncthreads();
    if (tid < 64) {
        const float nm = nomP[0][tid] + nomP[1][tid] + nomP[2][tid] + nomP[3][tid];
        const float dd = dnP[0] + dnP[1] + dnP[2] + dnP[3];
        const float adn = fmaxf(fabsf(dd), 1e-10f);
        const float sden = (dd >= 0.f) ? adn : -adn;
        const float m = nm / sden;
        float ss = wsum64(m * m);
        const float nn = fmaxf(sqrtf(ss), 1e-15f);
        const float s1 = tanhf(0.5f * artanh_c(nn));     // mobius_scalar_mul(0.5)
        const float res = s1 * m / nn;
        const float nres = fmaxf(s1, 1e-15f);            // ||res|| = s1 (s1 >= 0)
        const float l = (artanh_c(nres) / nres) * res;   // logmap0 over HD
        lc[((size_t)(bh * S_ + q)) * HD_ + tid] = l;
    }
}

// ---------------------------------------------------------------------------
// Stage 4: gather heads -> [B,Q,512] row, expmap0 over 512, store [S,B,HID].
// ---------------------------------------------------------------------------
__global__ __launch_bounds__(256) void outproj_kernel(
    const float* __restrict__ lc, float* __restrict__ out0)
{
    const int t = threadIdx.x;
    const int s = blockIdx.x & (S_ - 1);
    const int b = blockIdx.x >> 8;
    __shared__ float red[256];
    const int h0 = t >> 6, d0 = t & 63;
    const int e1 = t + 256;
    const int h1 = e1 >> 6, d1 = e1 & 63;
    const float v0 = lc[(((size_t)(b * NH_ + h0)) * S_ + s) * HD_ + d0];
    const float v1 = lc[(((size_t)(b * NH_ + h1)) * S_ + s) * HD_ + d1];
    const float ss = block_sum_256(v0 * v0 + v1 * v1, red);
    const float nn = fmaxf(sqrtf(ss), 1e-15f);
    const float f = tanhf(nn) / nn;
    float* orow = out0 + ((size_t)(s * B_ + b)) * HID_;
    orow[t] = f * v0;
    orow[t + 256] = f * v1;
}

extern "C" void kernel_launch(void* const* d_in, const int* in_sizes, int n_in,
                              void* d_out, int out_size, void* d_ws, size_t ws_size,
                              hipStream_t stream) {
    (void)in_sizes; (void)n_in; (void)out_size; (void)ws_size;
    const float* query = (const float*)d_in[0];
    const float* Wq = (const float*)d_in[1];
    const float* bq = (const float*)d_in[2];
    const float* Wk = (const float*)d_in[3];
    const float* bk = (const float*)d_in[4];
    const float* Wv = (const float*)d_in[5];
    const float* bv = (const float*)d_in[6];

    float* out0  = (float*)d_out;                          // [S,B,HID] = 262144
    float* probs = out0 + (size_t)S_ * B_ * HID_;          // [B,NH,S,S] = 1048576

    float* ws       = (float*)d_ws;
    float* ws_qkv   = ws;                                  // mx -> ql|kl|vl : 3*262144 floats
    float* ws_gamma = ws + (size_t)3 * BSH;                // 4096 floats, flat chunk order
    float* ws_lc    = ws_qkv;                              // alias ql (dead after scores)

    gemm3_kernel<<<dim3(3 * 128), dim3(256), 0, stream>>>(query, Wq, Wk, Wv, ws_qkv);
    mobius_rows_kernel<<<dim3(384), dim3(256), 0, stream>>>(query, bq, bk, bv, ws_qkv, ws_gamma);
    scores_kernel<<<dim3(512), dim3(256), 0, stream>>>(ws_qkv, probs);
    midpoint_kernel<<<dim3(B_ * NH_ * S_), dim3(256), 0, stream>>>(ws_qkv, ws_gamma, probs, ws_lc);
    outproj_kernel<<<dim3(B_ * S_), dim3(256), 0, stream>>>(ws_lc, out0);
}

// Round 4
// 129.979 us; speedup vs baseline: 1.7681x; 1.1047x over previous
//
#include <hip/hip_runtime.h>
#include <math.h>

// Problem constants (reference: S=256, B=2, HID=512, NH=8, HD=64, C=1)
constexpr int S_   = 256;
constexpr int B_   = 2;
constexpr int HID_ = 512;
constexpr int NH_  = 8;
constexpr int HD_  = 64;
constexpr int BSH  = B_ * S_ * HID_;   // 262144

__device__ __forceinline__ float artanh_c(float x) {
    // reference _artanh: clip to [-1+1e-7, 1-1e-7], then artanh
    x = fminf(fmaxf(x, -0.9999999f), 0.9999999f);
    return 0.5f * __logf((1.f + x) / (1.f - x));
}

__device__ __forceinline__ float wsum64(float v) {
    #pragma unroll
    for (int o = 1; o < 64; o <<= 1) v += __shfl_xor(v, o, 64);
    return v;
}

__device__ __forceinline__ float block_sum_256(float v, float* red) {
    const int t = threadIdx.x;
    __syncthreads();              // protect previous use of red
    red[t] = v;
    __syncthreads();
    #pragma unroll
    for (int sft = 128; sft > 0; sft >>= 1) {
        if (t < sft) red[t] += red[t + sft];
        __syncthreads();
    }
    return red[0];
}

// ---------------------------------------------------------------------------
// Stage 1a: mx = x @ W^T for all three weight matrices, as a tiled fp32 GEMM.
// x[row=b*S+s, i] = query[s*B+b, i]. Output ws_mx[which][row][col].
// Tiles: TM=32 rows x TN=64 cols, KC=32. Grid: 3 * 16 * 8 = 384 blocks.
// ---------------------------------------------------------------------------
constexpr int TM_ = 32, TN_ = 64, KC_ = 32;

__global__ __launch_bounds__(256) void gemm3_kernel(
    const float* __restrict__ query,
    const float* __restrict__ Wq, const float* __restrict__ Wk,
    const float* __restrict__ Wv, float* __restrict__ ws_mx)
{
    const int tid   = threadIdx.x;
    const int which = blockIdx.x >> 7;      // 128 tiles per matrix
    const int tmp   = blockIdx.x & 127;
    const int row0  = (tmp >> 3) * TM_;
    const int col0  = (tmp & 7) * TN_;
    const float* __restrict__ W = (which == 0) ? Wq : (which == 1) ? Wk : Wv;
    float* __restrict__ outp = ws_mx + (size_t)which * (HID_ * HID_);

    __shared__ __align__(16) float sA[KC_][68];   // [kk][row], padded
    __shared__ __align__(16) float sB[KC_][68];   // [kk][col], padded

    const int sr = tid >> 3;          // 0..31
    const int sk = (tid & 7) * 4;     // 0,4,...,28
    const int gra = row0 + sr;        // global x row (b*S+s)
    const float* pa  = query + (size_t)((gra & 255) * 2 + (gra >> 8)) * HID_ + sk;
    const float* pb0 = W + (size_t)(col0 + sr) * HID_ + sk;
    const float* pb1 = W + (size_t)(col0 + sr + 32) * HID_ + sk;

    const int ty = tid >> 4, tx = tid & 15;   // thread tile: rows ty*2+{0,1}, cols tx*4+{0..3}
    float acc[2][4] = {};

    float4 va  = *(const float4*)pa;
    float4 vb0 = *(const float4*)pb0;
    float4 vb1 = *(const float4*)pb1;
    for (int k0 = 0; k0 < HID_; k0 += KC_) {
        __syncthreads();
        sA[sk+0][sr] = va.x;  sA[sk+1][sr] = va.y;  sA[sk+2][sr] = va.z;  sA[sk+3][sr] = va.w;
        sB[sk+0][sr] = vb0.x; sB[sk+1][sr] = vb0.y; sB[sk+2][sr] = vb0.z; sB[sk+3][sr] = vb0.w;
        sB[sk+0][sr+32] = vb1.x; sB[sk+1][sr+32] = vb1.y; sB[sk+2][sr+32] = vb1.z; sB[sk+3][sr+32] = vb1.w;
        __syncthreads();
        if (k0 + KC_ < HID_) {            // prefetch next chunk, overlaps compute
            va  = *(const float4*)(pa + k0 + KC_);
            vb0 = *(const float4*)(pb0 + k0 + KC_);
            vb1 = *(const float4*)(pb1 + k0 + KC_);
        }
        #pragma unroll
        for (int kk = 0; kk < KC_; ++kk) {
            const float2 av = *(const float2*)&sA[kk][ty * 2];
            const float4 bv = *(const float4*)&sB[kk][tx * 4];
            acc[0][0] = fmaf(av.x, bv.x, acc[0][0]);
            acc[0][1] = fmaf(av.x, bv.y, acc[0][1]);
            acc[0][2] = fmaf(av.x, bv.z, acc[0][2]);
            acc[0][3] = fmaf(av.x, bv.w, acc[0][3]);
            acc[1][0] = fmaf(av.y, bv.x, acc[1][0]);
            acc[1][1] = fmaf(av.y, bv.y, acc[1][1]);
            acc[1][2] = fmaf(av.y, bv.z, acc[1][2]);
            acc[1][3] = fmaf(av.y, bv.w, acc[1][3]);
        }
    }
    #pragma unroll
    for (int i = 0; i < 2; ++i) {
        float4 o = make_float4(acc[i][0], acc[i][1], acc[i][2], acc[i][3]);
        *(float4*)&outp[(size_t)(row0 + ty * 2 + i) * HID_ + col0 + tx * 4] = o;
    }
}

// ---------------------------------------------------------------------------
// Stage 1b: per-row mobius epilogue, ONE WAVE PER ROW (no barriers).
// In-place: reads mx row from ws_qkv, writes q/k/v (logmap0+chunk expmap0).
// gamma stored in FLAT CHUNK ORDER: ws_gamma[(b*S+s)*NH + j] — identical to
// [b][h][n] flat indexing through the reshape identity (chunk c=s*8+j=h*256+n).
// ---------------------------------------------------------------------------
__global__ __launch_bounds__(256) void mobius_rows_kernel(
    const float* __restrict__ query,
    const float* __restrict__ bq, const float* __restrict__ bk,
    const float* __restrict__ bv,
    float* __restrict__ ws_qkv, float* __restrict__ ws_gamma)
{
    const int lane = threadIdx.x & 63;
    const int wv   = threadIdx.x >> 6;
    const int row  = blockIdx.x * 4 + wv;     // 0..1535
    const int which = row >> 9;
    const int rr    = row & 511;              // b*S + s
    const float* __restrict__ bias = (which == 0) ? bq : (which == 1) ? bk : bv;
    float* mrow = ws_qkv + (size_t)row * HID_;
    const float* xrow = query + (size_t)((rr & 255) * 2 + (rr >> 8)) * HID_;

    float m[8], x[8], bb[8];
    *(float4*)&m[0]  = ((const float4*)mrow)[lane * 2];
    *(float4*)&m[4]  = ((const float4*)mrow)[lane * 2 + 1];
    *(float4*)&x[0]  = ((const float4*)xrow)[lane * 2];
    *(float4*)&x[4]  = ((const float4*)xrow)[lane * 2 + 1];
    *(float4*)&bb[0] = ((const float4*)bias)[lane * 2];
    *(float4*)&bb[4] = ((const float4*)bias)[lane * 2 + 1];

    float x2p = 0.f, m2p = 0.f, b2p = 0.f;
    #pragma unroll
    for (int j = 0; j < 8; ++j) {
        x2p = fmaf(x[j], x[j], x2p);
        m2p = fmaf(m[j], m[j], m2p);
        b2p = fmaf(bb[j], bb[j], b2p);
    }
    const float x2s = wsum64(x2p);
    const float mn2 = wsum64(m2p);
    const float b2s = wsum64(b2p);
    const float xn = fmaxf(sqrtf(x2s), 1e-15f);
    const float mn = fmaxf(sqrtf(mn2), 1e-15f);
    // mobius_matvec: res = tanh(mn/xn * artanh(xn)) * mx/mn
    const float fac = tanhf(mn / xn * artanh_c(xn)) / mn;
    float r[8];
    float r2p = 0.f, ryp = 0.f;
    #pragma unroll
    for (int j = 0; j < 8; ++j) {
        r[j] = fac * m[j];
        r2p = fmaf(r[j], r[j], r2p);
        ryp = fmaf(r[j], bb[j], ryp);
    }
    const float r2s = wsum64(r2p);
    const float ry  = wsum64(ryp);
    // mobius_add(r, bias)
    const float a_c = 1.f + 2.f * ry + b2s;
    const float b_c = 1.f - r2s;
    const float den = 1.f + 2.f * ry + r2s * b2s;
    const float inv_den = 1.f / fmaxf(den, 1e-15f);
    float h[8];
    float h2p = 0.f;
    #pragma unroll
    for (int j = 0; j < 8; ++j) {
        h[j] = (a_c * r[j] + b_c * bb[j]) * inv_den;
        h2p = fmaf(h[j], h[j], h2p);
    }
    const float h2s = wsum64(h2p);
    float hn = fmaxf(sqrtf(h2s), 1e-15f);
    float pf = 1.f;
    if (hn > 0.996f) { pf = 0.996f / hn; hn = 0.996f; }   // projx
    const float lf = artanh_c(hn) / hn * pf;               // logmap0 (512-dim)
    float l[8];
    float l2p = 0.f;
    #pragma unroll
    for (int j = 0; j < 8; ++j) {
        l[j] = lf * h[j];
        l2p = fmaf(l[j], l[j], l2p);
    }
    // expmap0 over flat 64-chunks: chunk j = lanes j*8 .. j*8+7
    float cs = l2p;
    cs += __shfl_xor(cs, 1, 64);
    cs += __shfl_xor(cs, 2, 64);
    cs += __shfl_xor(cs, 4, 64);
    const float cn = fmaxf(sqrtf(cs), 1e-15f);
    const float th = tanhf(cn);
    const float sc = th / cn;
    float o[8];
    #pragma unroll
    for (int j = 0; j < 8; ++j) o[j] = sc * l[j];
    ((float4*)mrow)[lane * 2]     = *(float4*)&o[0];
    ((float4*)mrow)[lane * 2 + 1] = *(float4*)&o[4];
    if (which == 2 && (lane & 7) == 0) {
        const int j = lane >> 3;
        // gamma = 2 / max(1 - ||vl_chunk||^2, eps); ||vl_chunk|| = tanh(cn)
        ws_gamma[(size_t)rr * NH_ + j] = 2.f / fmaxf(1.f - th * th, 1e-15f);
    }
}

// ---------------------------------------------------------------------------
// Stage 2+3 FUSED: scores/probs + weighted gyro-midpoint + scalar_mul + logmap0.
// Block = (bh, 8-q tile), 512 blocks x 256 threads.
// Phase A (scores): K staged in two 128-row LDS halves (XOR-swizzled);
//   p -> probs (global, output 1) and p*gamma -> pS (LDS); sp/spg running sums.
// Phase B (midpoint): wave w handles q rows {w, w+4}, lane = d;
//   nom[q,d] = sum_n pS[q][n]*vl[n,d] via broadcast LDS reads + coalesced vl.
// NOTE: lc must NOT alias ql (other blocks still read ql in phase A).
// ---------------------------------------------------------------------------
__global__ __launch_bounds__(256) void attn_kernel(
    const float* __restrict__ ws_qkv, const float* __restrict__ gamma,
    float* __restrict__ probs, float* __restrict__ lc)
{
    const int tid = threadIdx.x;
    const int bh  = blockIdx.x >> 5;
    const int q0  = (blockIdx.x & 31) * 8;
    const float* __restrict__ ql = ws_qkv + (size_t)bh * (S_ * HD_);
    const float* __restrict__ kl = ws_qkv + (size_t)BSH + (size_t)bh * (S_ * HD_);
    const float* __restrict__ vl = ws_qkv + (size_t)2 * BSH + (size_t)bh * (S_ * HD_);

    __shared__ __align__(16) float kS[128 * 64];   // 32 KB, swizzled
    __shared__ __align__(16) float qS[8 * 64];     // 2 KB
    __shared__ float pS[8 * 256];                  // 8 KB: p*gamma, [q_local][n]
    __shared__ float gS[S_];                       // 1 KB
    __shared__ float dnS[8];

    // gamma in flat-chunk order == [b][h][n] flat => contiguous at bh*S_
    gS[tid] = gamma[(size_t)bh * S_ + tid];
    if (tid < 128) ((float4*)qS)[tid] = ((const float4*)(ql + (size_t)q0 * 64))[tid];
    __syncthreads();

    const int q_l = tid >> 5;       // 0..7
    const int n_i = tid & 31;       // 0..31
    float qv[64];
    #pragma unroll
    for (int c = 0; c < 16; ++c)
        *(float4*)&qv[c * 4] = *(const float4*)&qS[q_l * 64 + c * 4];
    float q2 = 0.f;
    #pragma unroll
    for (int d = 0; d < 64; ++d) q2 = fmaf(qv[d], qv[d], q2);
    const float b_c = 1.f - q2;
    float* __restrict__ prow = probs + ((size_t)(bh * S_ + q0 + q_l)) * S_;

    const int c4 = tid & 15;        // staging: chunk
    const int nb = tid >> 4;        // staging: row base
    float sp = 0.f, spg = 0.f;

    for (int half = 0; half < 2; ++half) {
        __syncthreads();            // protect kS reuse across halves
        #pragma unroll
        for (int jj = 0; jj < 8; ++jj) {
            const int n = nb + 16 * jj;   // 0..127
            const float4 v = *(const float4*)(kl + ((size_t)(half * 128 + n)) * 64 + c4 * 4);
            *(float4*)&kS[n * 64 + ((c4 ^ (n & 15)) * 4)] = v;
        }
        __syncthreads();
        #pragma unroll
        for (int j = 0; j < 4; ++j) {
            const int n = n_i + 32 * j;   // within half
            float kv[64];
            #pragma unroll
            for (int c = 0; c < 16; ++c)
                *(float4*)&kv[c * 4] = *(const float4*)&kS[n * 64 + ((c ^ (n & 15)) * 4)];
            float s = 0.f, k2 = 0.f;
            #pragma unroll
            for (int d = 0; d < 64; ++d) {
                s  = fmaf(qv[d], kv[d], s);
                k2 = fmaf(kv[d], kv[d], k2);
            }
            const float a_c = 1.f - 2.f * s + k2;
            const float den = fmaxf(fmaf(q2, k2, 1.f - 2.f * s), 1e-15f);
            const float c2  = 1e-30f * den * den;
            float invsum = 0.f;
            #pragma unroll
            for (int d = 0; d < 64; ++d) {
                const float u = fmaf(b_c, kv[d], -(a_c * qv[d]));
                invsum += __builtin_amdgcn_rcpf(fmaf(u, u, c2));
            }
            const float t1 = __builtin_amdgcn_rsqf(den * den * invsum);
            const float p = 0.5f - 0.5f * fminf(t1, 0.9999999f);
            const int gn = half * 128 + n;
            prow[gn] = p;
            const float g = gS[gn];
            pS[q_l * 256 + gn] = p * g;
            sp += p; spg += p * g;
        }
    }
    // reduce sp/spg over the 32 threads sharing q_l (lanes [0,32) / [32,64))
    #pragma unroll
    for (int o = 1; o < 32; o <<= 1) {
        sp  += __shfl_xor(sp, o, 64);
        spg += __shfl_xor(spg, o, 64);
    }
    if ((tid & 31) == 0) dnS[q_l] = spg - sp;   // denom = sum p*(g-1)
    __syncthreads();

    // Phase B: wave w -> q rows {w, w+4}; lane = d
    const int w = tid >> 6, d = tid & 63;
    const float* __restrict__ p0 = &pS[w * 256];
    const float* __restrict__ p1 = &pS[(w + 4) * 256];
    float acc0 = 0.f, acc1 = 0.f;
    #pragma unroll 8
    for (int n = 0; n < 256; ++n) {
        const float v = vl[(size_t)n * 64 + d];
        acc0 = fmaf(p0[n], v, acc0);
        acc1 = fmaf(p1[n], v, acc1);
    }
    #pragma unroll
    for (int t = 0; t < 2; ++t) {
        const int qq = w + 4 * t;
        const float nom = t ? acc1 : acc0;
        const float dd = dnS[qq];
        const float adn = fmaxf(fabsf(dd), 1e-10f);
        const float sden = (dd >= 0.f) ? adn : -adn;
        const float m = nom / sden;
        const float ss = wsum64(m * m);
        const float nn = fmaxf(sqrtf(ss), 1e-15f);
        const float s1 = tanhf(0.5f * artanh_c(nn));     // mobius_scalar_mul(0.5)
        const float res = s1 * m / nn;
        const float nres = fmaxf(s1, 1e-15f);            // ||res|| = s1 >= 0
        lc[((size_t)(bh * S_ + q0 + qq)) * HD_ + d] = (artanh_c(nres) / nres) * res;
    }
}

// ---------------------------------------------------------------------------
// Stage 4: gather heads -> [B,Q,512] row, expmap0 over 512, store [S,B,HID].
// ---------------------------------------------------------------------------
__global__ __launch_bounds__(256) void outproj_kernel(
    const float* __restrict__ lc, float* __restrict__ out0)
{
    const int t = threadIdx.x;
    const int s = blockIdx.x & (S_ - 1);
    const int b = blockIdx.x >> 8;
    __shared__ float red[256];
    const int h0 = t >> 6, d0 = t & 63;
    const int e1 = t + 256;
    const int h1 = e1 >> 6, d1 = e1 & 63;
    const float v0 = lc[(((size_t)(b * NH_ + h0)) * S_ + s) * HD_ + d0];
    const float v1 = lc[(((size_t)(b * NH_ + h1)) * S_ + s) * HD_ + d1];
    const float ss = block_sum_256(v0 * v0 + v1 * v1, red);
    const float nn = fmaxf(sqrtf(ss), 1e-15f);
    const float f = tanhf(nn) / nn;
    float* orow = out0 + ((size_t)(s * B_ + b)) * HID_;
    orow[t] = f * v0;
    orow[t + 256] = f * v1;
}

extern "C" void kernel_launch(void* const* d_in, const int* in_sizes, int n_in,
                              void* d_out, int out_size, void* d_ws, size_t ws_size,
                              hipStream_t stream) {
    (void)in_sizes; (void)n_in; (void)out_size; (void)ws_size;
    const float* query = (const float*)d_in[0];
    const float* Wq = (const float*)d_in[1];
    const float* bq = (const float*)d_in[2];
    const float* Wk = (const float*)d_in[3];
    const float* bk = (const float*)d_in[4];
    const float* Wv = (const float*)d_in[5];
    const float* bv = (const float*)d_in[6];

    float* out0  = (float*)d_out;                          // [S,B,HID] = 262144
    float* probs = out0 + (size_t)S_ * B_ * HID_;          // [B,NH,S,S] = 1048576

    float* ws       = (float*)d_ws;
    float* ws_qkv   = ws;                                  // mx -> ql|kl|vl : 3*262144 floats
    float* ws_gamma = ws + (size_t)3 * BSH;                // 4096 floats, flat chunk order
    float* ws_lc    = ws + (size_t)3 * BSH + 4096;         // 131072 floats (NO alias: attn
                                                           // writes lc while other blocks read ql)

    gemm3_kernel<<<dim3(3 * 128), dim3(256), 0, stream>>>(query, Wq, Wk, Wv, ws_qkv);
    mobius_rows_kernel<<<dim3(384), dim3(256), 0, stream>>>(query, bq, bk, bv, ws_qkv, ws_gamma);
    attn_kernel<<<dim3(512), dim3(256), 0, stream>>>(ws_qkv, ws_gamma, probs, ws_lc);
    outproj_kernel<<<dim3(B_ * S_), dim3(256), 0, stream>>>(ws_lc, out0);
}

// Round 5
// 129.322 us; speedup vs baseline: 1.7771x; 1.0051x over previous
//
#include <hip/hip_runtime.h>
#include <math.h>

// Problem constants (reference: S=256, B=2, HID=512, NH=8, HD=64, C=1)
constexpr int S_   = 256;
constexpr int B_   = 2;
constexpr int HID_ = 512;
constexpr int NH_  = 8;
constexpr int HD_  = 64;
constexpr int BSH  = B_ * S_ * HID_;   // 262144

__device__ __forceinline__ float artanh_c(float x) {
    // reference _artanh: clip to [-1+1e-7, 1-1e-7], then artanh
    x = fminf(fmaxf(x, -0.9999999f), 0.9999999f);
    return 0.5f * __logf((1.f + x) / (1.f - x));
}

__device__ __forceinline__ float wsum64(float v) {
    #pragma unroll
    for (int o = 1; o < 64; o <<= 1) v += __shfl_xor(v, o, 64);
    return v;
}

__device__ __forceinline__ float block_sum_256(float v, float* red) {
    const int t = threadIdx.x;
    __syncthreads();              // protect previous use of red
    red[t] = v;
    __syncthreads();
    #pragma unroll
    for (int sft = 128; sft > 0; sft >>= 1) {
        if (t < sft) red[t] += red[t + sft];
        __syncthreads();
    }
    return red[0];
}

// ---------------------------------------------------------------------------
// Stage 1a: mx = x @ W^T for all three weight matrices, tiled fp32 GEMM.
// x[row=b*S+s, i] = query[s*B+b, i]. Output ws_mx[which][row][col].
// TM=TN=32, KC=32 -> 3 * 16 * 16 = 768 blocks = exactly 3 blocks/CU (balanced;
// the previous 384-block config left half the CUs with 2 blocks, half with 1).
// ---------------------------------------------------------------------------
__global__ __launch_bounds__(256) void gemm3_kernel(
    const float* __restrict__ query,
    const float* __restrict__ Wq, const float* __restrict__ Wk,
    const float* __restrict__ Wv, float* __restrict__ ws_mx)
{
    const int tid   = threadIdx.x;
    const int which = blockIdx.x >> 8;      // 256 tiles per matrix
    const int tmp   = blockIdx.x & 255;
    const int row0  = (tmp >> 4) * 32;
    const int col0  = (tmp & 15) * 32;
    const float* __restrict__ W = (which == 0) ? Wq : (which == 1) ? Wk : Wv;
    float* __restrict__ outp = ws_mx + (size_t)which * (HID_ * HID_);

    __shared__ __align__(16) float sA[32][36];   // [kk][row], padded
    __shared__ __align__(16) float sB[32][36];   // [kk][col], padded

    const int sr = tid >> 3;          // 0..31
    const int sk = (tid & 7) * 4;     // 0,4,...,28
    const int gra = row0 + sr;        // global x row (b*S+s)
    const float* pa = query + (size_t)((gra & 255) * 2 + (gra >> 8)) * HID_ + sk;
    const float* pb = W + (size_t)(col0 + sr) * HID_ + sk;

    const int ty = tid >> 4, tx = tid & 15;   // rows ty*2+{0,1}, cols tx*2+{0,1}
    float acc[2][2] = {};

    float4 va = *(const float4*)pa;
    float4 vb = *(const float4*)pb;
    for (int k0 = 0; k0 < HID_; k0 += 32) {
        __syncthreads();
        sA[sk+0][sr] = va.x; sA[sk+1][sr] = va.y; sA[sk+2][sr] = va.z; sA[sk+3][sr] = va.w;
        sB[sk+0][sr] = vb.x; sB[sk+1][sr] = vb.y; sB[sk+2][sr] = vb.z; sB[sk+3][sr] = vb.w;
        __syncthreads();
        if (k0 + 32 < HID_) {             // prefetch next chunk, overlaps compute
            va = *(const float4*)(pa + k0 + 32);
            vb = *(const float4*)(pb + k0 + 32);
        }
        #pragma unroll
        for (int kk = 0; kk < 32; ++kk) {
            const float2 av = *(const float2*)&sA[kk][ty * 2];   // broadcast (4 addrs/wave)
            const float2 bv = *(const float2*)&sB[kk][tx * 2];   // 16 addrs x b64 = clean
            acc[0][0] = fmaf(av.x, bv.x, acc[0][0]);
            acc[0][1] = fmaf(av.x, bv.y, acc[0][1]);
            acc[1][0] = fmaf(av.y, bv.x, acc[1][0]);
            acc[1][1] = fmaf(av.y, bv.y, acc[1][1]);
        }
    }
    #pragma unroll
    for (int i = 0; i < 2; ++i) {
        *(float2*)&outp[(size_t)(row0 + ty * 2 + i) * HID_ + col0 + tx * 2] =
            make_float2(acc[i][0], acc[i][1]);
    }
}

// ---------------------------------------------------------------------------
// Stage 1b: per-row mobius epilogue, ONE WAVE PER ROW (no barriers).
// In-place: reads mx row from ws_qkv, writes q/k/v (logmap0+chunk expmap0).
// gamma stored in FLAT CHUNK ORDER: ws_gamma[(b*S+s)*NH + j] — identical to
// [b][h][n] flat indexing through the reshape identity (chunk c=s*8+j=h*256+n).
// ---------------------------------------------------------------------------
__global__ __launch_bounds__(256) void mobius_rows_kernel(
    const float* __restrict__ query,
    const float* __restrict__ bq, const float* __restrict__ bk,
    const float* __restrict__ bv,
    float* __restrict__ ws_qkv, float* __restrict__ ws_gamma)
{
    const int lane = threadIdx.x & 63;
    const int wv   = threadIdx.x >> 6;
    const int row  = blockIdx.x * 4 + wv;     // 0..1535
    const int which = row >> 9;
    const int rr    = row & 511;              // b*S + s
    const float* __restrict__ bias = (which == 0) ? bq : (which == 1) ? bk : bv;
    float* mrow = ws_qkv + (size_t)row * HID_;
    const float* xrow = query + (size_t)((rr & 255) * 2 + (rr >> 8)) * HID_;

    float m[8], x[8], bb[8];
    *(float4*)&m[0]  = ((const float4*)mrow)[lane * 2];
    *(float4*)&m[4]  = ((const float4*)mrow)[lane * 2 + 1];
    *(float4*)&x[0]  = ((const float4*)xrow)[lane * 2];
    *(float4*)&x[4]  = ((const float4*)xrow)[lane * 2 + 1];
    *(float4*)&bb[0] = ((const float4*)bias)[lane * 2];
    *(float4*)&bb[4] = ((const float4*)bias)[lane * 2 + 1];

    float x2p = 0.f, m2p = 0.f, b2p = 0.f;
    #pragma unroll
    for (int j = 0; j < 8; ++j) {
        x2p = fmaf(x[j], x[j], x2p);
        m2p = fmaf(m[j], m[j], m2p);
        b2p = fmaf(bb[j], bb[j], b2p);
    }
    const float x2s = wsum64(x2p);
    const float mn2 = wsum64(m2p);
    const float b2s = wsum64(b2p);
    const float xn = fmaxf(sqrtf(x2s), 1e-15f);
    const float mn = fmaxf(sqrtf(mn2), 1e-15f);
    // mobius_matvec: res = tanh(mn/xn * artanh(xn)) * mx/mn
    const float fac = tanhf(mn / xn * artanh_c(xn)) / mn;
    float r[8];
    float r2p = 0.f, ryp = 0.f;
    #pragma unroll
    for (int j = 0; j < 8; ++j) {
        r[j] = fac * m[j];
        r2p = fmaf(r[j], r[j], r2p);
        ryp = fmaf(r[j], bb[j], ryp);
    }
    const float r2s = wsum64(r2p);
    const float ry  = wsum64(ryp);
    // mobius_add(r, bias)
    const float a_c = 1.f + 2.f * ry + b2s;
    const float b_c = 1.f - r2s;
    const float den = 1.f + 2.f * ry + r2s * b2s;
    const float inv_den = 1.f / fmaxf(den, 1e-15f);
    float h[8];
    float h2p = 0.f;
    #pragma unroll
    for (int j = 0; j < 8; ++j) {
        h[j] = (a_c * r[j] + b_c * bb[j]) * inv_den;
        h2p = fmaf(h[j], h[j], h2p);
    }
    const float h2s = wsum64(h2p);
    float hn = fmaxf(sqrtf(h2s), 1e-15f);
    float pf = 1.f;
    if (hn > 0.996f) { pf = 0.996f / hn; hn = 0.996f; }   // projx
    const float lf = artanh_c(hn) / hn * pf;               // logmap0 (512-dim)
    float l[8];
    float l2p = 0.f;
    #pragma unroll
    for (int j = 0; j < 8; ++j) {
        l[j] = lf * h[j];
        l2p = fmaf(l[j], l[j], l2p);
    }
    // expmap0 over flat 64-chunks: chunk j = lanes j*8 .. j*8+7
    float cs = l2p;
    cs += __shfl_xor(cs, 1, 64);
    cs += __shfl_xor(cs, 2, 64);
    cs += __shfl_xor(cs, 4, 64);
    const float cn = fmaxf(sqrtf(cs), 1e-15f);
    const float th = tanhf(cn);
    const float sc = th / cn;
    float o[8];
    #pragma unroll
    for (int j = 0; j < 8; ++j) o[j] = sc * l[j];
    ((float4*)mrow)[lane * 2]     = *(float4*)&o[0];
    ((float4*)mrow)[lane * 2 + 1] = *(float4*)&o[4];
    if (which == 2 && (lane & 7) == 0) {
        const int j = lane >> 3;
        // gamma = 2 / max(1 - ||vl_chunk||^2, eps); ||vl_chunk|| = tanh(cn)
        ws_gamma[(size_t)rr * NH_ + j] = 2.f / fmaxf(1.f - th * th, 1e-15f);
    }
}

// ---------------------------------------------------------------------------
// Stage 2+3 FUSED: scores/probs + weighted gyro-midpoint + scalar_mul + logmap0.
// Block = (bh, 8-q tile), 512 blocks x 256 threads.
// Phase A: K staged in two 128-row LDS halves (XOR-swizzled); per-row |k|^2
//   precomputed during staging (k2 is q-independent — was computed 8x).
//   u-loop factored: u = a_c*(r_c*k - q), r_c = b_c/a_c (a_c>0 strictly since
//   |q|,|k|<1: a_c = (1-|k|)^2 + 2|k|(1-|q|·cos) > 0), so
//   sum 1/(u^2+c2) = (1/a_c^2) * sum 1/(w^2 + c2/a_c^2): 3 VALU + rcp per d.
// Phase B: wave w owns n in [64w,64w+64) for ALL 8 q (vl read once per block,
//   not 4x), partials combined via LDS.
// NOTE: lc must NOT alias ql (other blocks still read ql in phase A).
// ---------------------------------------------------------------------------
__global__ __launch_bounds__(256) void attn_kernel(
    const float* __restrict__ ws_qkv, const float* __restrict__ gamma,
    float* __restrict__ probs, float* __restrict__ lc)
{
    const int tid = threadIdx.x;
    const int bh  = blockIdx.x >> 5;
    const int q0  = (blockIdx.x & 31) * 8;
    const float* __restrict__ ql = ws_qkv + (size_t)bh * (S_ * HD_);
    const float* __restrict__ kl = ws_qkv + (size_t)BSH + (size_t)bh * (S_ * HD_);
    const float* __restrict__ vl = ws_qkv + (size_t)2 * BSH + (size_t)bh * (S_ * HD_);

    __shared__ __align__(16) float kS[128 * 64];   // 32 KB, swizzled
    __shared__ __align__(16) float qS[8 * 64];     // 2 KB
    __shared__ __align__(16) float pS[8 * 256];    // 8 KB: p*gamma, [q_local][n]
    __shared__ float gS[S_];                       // 1 KB
    __shared__ float k2S[128];                     // per-row |k|^2, per half
    __shared__ float nomP[4][8][64];               // 8 KB phase-B partials
    __shared__ float dnS[8];

    // gamma in flat-chunk order == [b][h][n] flat => contiguous at bh*S_
    gS[tid] = gamma[(size_t)bh * S_ + tid];
    if (tid < 128) ((float4*)qS)[tid] = ((const float4*)(ql + (size_t)q0 * 64))[tid];
    __syncthreads();

    const int q_l = tid >> 5;       // 0..7
    const int n_i = tid & 31;       // 0..31
    float qv[64];
    #pragma unroll
    for (int c = 0; c < 16; ++c)
        *(float4*)&qv[c * 4] = *(const float4*)&qS[q_l * 64 + c * 4];
    float q2 = 0.f;
    #pragma unroll
    for (int d = 0; d < 64; ++d) q2 = fmaf(qv[d], qv[d], q2);
    const float b_c = 1.f - q2;
    float* __restrict__ prow = probs + ((size_t)(bh * S_ + q0 + q_l)) * S_;

    const int c4 = tid & 15;        // staging: chunk
    const int nb = tid >> 4;        // staging: row base
    float sp = 0.f, spg = 0.f;

    for (int half = 0; half < 2; ++half) {
        __syncthreads();            // protect kS/k2S reuse across halves
        #pragma unroll
        for (int jj = 0; jj < 8; ++jj) {
            const int n = nb + 16 * jj;   // 0..127
            const float4 v = *(const float4*)(kl + ((size_t)(half * 128 + n)) * 64 + c4 * 4);
            *(float4*)&kS[n * 64 + ((c4 ^ (n & 15)) * 4)] = v;
            // per-row |k|^2: reduce 16 chunk-partials over the 16 lanes sharing nb
            float pk = fmaf(v.x, v.x, fmaf(v.y, v.y, fmaf(v.z, v.z, v.w * v.w)));
            pk += __shfl_xor(pk, 1, 64);
            pk += __shfl_xor(pk, 2, 64);
            pk += __shfl_xor(pk, 4, 64);
            pk += __shfl_xor(pk, 8, 64);
            if (c4 == 0) k2S[n] = pk;
        }
        __syncthreads();
        #pragma unroll
        for (int j = 0; j < 4; ++j) {
            const int n = n_i + 32 * j;   // within half
            float kv[64];
            #pragma unroll
            for (int c = 0; c < 16; ++c)
                *(float4*)&kv[c * 4] = *(const float4*)&kS[n * 64 + ((c ^ (n & 15)) * 4)];
            float s = 0.f;
            #pragma unroll
            for (int d = 0; d < 64; ++d) s = fmaf(qv[d], kv[d], s);
            const float k2  = k2S[n];
            const float a_c = 1.f - 2.f * s + k2;
            const float den = fmaxf(fmaf(q2, k2, 1.f - 2.f * s), 1e-15f);
            const float ra  = __builtin_amdgcn_rcpf(a_c);
            const float r_c = b_c * ra;
            const float scale = den * den * ra * ra;   // den^2 / a_c^2
            const float c2  = 1e-30f * scale;
            float invsum = 0.f;
            #pragma unroll
            for (int d = 0; d < 64; ++d) {
                const float w = fmaf(r_c, kv[d], -qv[d]);
                invsum += __builtin_amdgcn_rcpf(fmaf(w, w, c2));
            }
            const float t1 = __builtin_amdgcn_rsqf(scale * invsum);
            const float p = 0.5f - 0.5f * fminf(t1, 0.9999999f);
            const int gn = half * 128 + n;
            prow[gn] = p;
            const float g = gS[gn];
            pS[q_l * 256 + gn] = p * g;
            sp += p; spg += p * g;
        }
    }
    // reduce sp/spg over the 32 threads sharing q_l (lanes [0,32) / [32,64))
    #pragma unroll
    for (int o = 1; o < 32; o <<= 1) {
        sp  += __shfl_xor(sp, o, 64);
        spg += __shfl_xor(spg, o, 64);
    }
    if ((tid & 31) == 0) dnS[q_l] = spg - sp;   // denom = sum p*(g-1)
    __syncthreads();

    // Phase B: wave w owns n in [64w, 64w+64), all 8 q; lane = d
    const int w = tid >> 6, d = tid & 63;
    float acc[8] = {};
    const float* __restrict__ vbase = vl + (size_t)(w * 64) * 64;
    #pragma unroll 4
    for (int i4 = 0; i4 < 16; ++i4) {
        float vv[4];
        #pragma unroll
        for (int j2 = 0; j2 < 4; ++j2) vv[j2] = vbase[(size_t)(i4 * 4 + j2) * 64 + d];
        #pragma unroll
        for (int qq = 0; qq < 8; ++qq) {
            const float4 pq = *(const float4*)&pS[qq * 256 + w * 64 + i4 * 4]; // broadcast
            acc[qq] = fmaf(pq.x, vv[0], acc[qq]);
            acc[qq] = fmaf(pq.y, vv[1], acc[qq]);
            acc[qq] = fmaf(pq.z, vv[2], acc[qq]);
            acc[qq] = fmaf(pq.w, vv[3], acc[qq]);
        }
    }
    #pragma unroll
    for (int qq = 0; qq < 8; ++qq) nomP[w][qq][d] = acc[qq];
    __syncthreads();

    #pragma unroll
    for (int t = 0; t < 2; ++t) {
        const int qq = (tid >> 6) + 4 * t;
        const float nom = nomP[0][qq][d] + nomP[1][qq][d] + nomP[2][qq][d] + nomP[3][qq][d];
        const float dd = dnS[qq];
        const float adn = fmaxf(fabsf(dd), 1e-10f);
        const float sden = (dd >= 0.f) ? adn : -adn;
        const float m = nom / sden;
        const float ss = wsum64(m * m);
        const float nn = fmaxf(sqrtf(ss), 1e-15f);
        const float s1 = tanhf(0.5f * artanh_c(nn));     // mobius_scalar_mul(0.5)
        const float res = s1 * m / nn;
        const float nres = fmaxf(s1, 1e-15f);            // ||res|| = s1 >= 0
        lc[((size_t)(bh * S_ + q0 + qq)) * HD_ + d] = (artanh_c(nres) / nres) * res;
    }
}

// ---------------------------------------------------------------------------
// Stage 4: gather heads -> [B,Q,512] row, expmap0 over 512, store [S,B,HID].
// ---------------------------------------------------------------------------
__global__ __launch_bounds__(256) void outproj_kernel(
    const float* __restrict__ lc, float* __restrict__ out0)
{
    const int t = threadIdx.x;
    const int s = blockIdx.x & (S_ - 1);
    const int b = blockIdx.x >> 8;
    __shared__ float red[256];
    const int h0 = t >> 6, d0 = t & 63;
    const int e1 = t + 256;
    const int h1 = e1 >> 6, d1 = e1 & 63;
    const float v0 = lc[(((size_t)(b * NH_ + h0)) * S_ + s) * HD_ + d0];
    const float v1 = lc[(((size_t)(b * NH_ + h1)) * S_ + s) * HD_ + d1];
    const float ss = block_sum_256(v0 * v0 + v1 * v1, red);
    const float nn = fmaxf(sqrtf(ss), 1e-15f);
    const float f = tanhf(nn) / nn;
    float* orow = out0 + ((size_t)(s * B_ + b)) * HID_;
    orow[t] = f * v0;
    orow[t + 256] = f * v1;
}

extern "C" void kernel_launch(void* const* d_in, const int* in_sizes, int n_in,
                              void* d_out, int out_size, void* d_ws, size_t ws_size,
                              hipStream_t stream) {
    (void)in_sizes; (void)n_in; (void)out_size; (void)ws_size;
    const float* query = (const float*)d_in[0];
    const float* Wq = (const float*)d_in[1];
    const float* bq = (const float*)d_in[2];
    const float* Wk = (const float*)d_in[3];
    const float* bk = (const float*)d_in[4];
    const float* Wv = (const float*)d_in[5];
    const float* bv = (const float*)d_in[6];

    float* out0  = (float*)d_out;                          // [S,B,HID] = 262144
    float* probs = out0 + (size_t)S_ * B_ * HID_;          // [B,NH,S,S] = 1048576

    float* ws       = (float*)d_ws;
    float* ws_qkv   = ws;                                  // mx -> ql|kl|vl : 3*262144 floats
    float* ws_gamma = ws + (size_t)3 * BSH;                // 4096 floats, flat chunk order
    float* ws_lc    = ws + (size_t)3 * BSH + 4096;         // 131072 floats (NO alias: attn
                                                           // writes lc while other blocks read ql)

    gemm3_kernel<<<dim3(768), dim3(256), 0, stream>>>(query, Wq, Wk, Wv, ws_qkv);
    mobius_rows_kernel<<<dim3(384), dim3(256), 0, stream>>>(query, bq, bk, bv, ws_qkv, ws_gamma);
    attn_kernel<<<dim3(512), dim3(256), 0, stream>>>(ws_qkv, ws_gamma, probs, ws_lc);
    outproj_kernel<<<dim3(B_ * S_), dim3(256), 0, stream>>>(ws_lc, out0);
}